// Round 1
// baseline (1505.946 us; speedup 1.0000x reference)
//
#include <hip/hip_runtime.h>
#include <hip/hip_bf16.h>

// WindowAttention (Swin) on MI355X — round 1 (correctness-first bf16-MFMA pipeline)
//   K1 k_qkv : qkv = x @ Wqkv + b   (bf16 MFMA 64x64 tiles) -> ws (bf16)
//   K2 k_attn: per-window attention (MFMA 16x16x32, wave-parallel softmax),
//              O written into the q-columns of ws
//   K3 k_proj: out = O @ Wproj + b  (fp32 output)
// ws demand: 462.4 MB; chunked by ws_size in units of 64 windows (7.2 MB/unit).

typedef __attribute__((ext_vector_type(8))) short bf16x8;
typedef __attribute__((ext_vector_type(4))) float f32x4;

#define SEQ_N  49
#define CH     384
#define QKV_N  1152
#define HDIM   32
#define UNIT_WIN  64
#define UNIT_ROWS 3136   // 64 windows * 49 rows

__device__ __forceinline__ unsigned short f2b(float f) {
    union { float f; unsigned int u; } v; v.f = f;
    return (unsigned short)((v.u + 0x7FFFu + ((v.u >> 16) & 1u)) >> 16);
}

__device__ __forceinline__ bf16x8 ld8(const unsigned short* p) {
    const ushort4* p4 = (const ushort4*)p;   // 8B-aligned at every call site
    ushort4 a = p4[0], b = p4[1];
    bf16x8 r;
    r[0] = (short)a.x; r[1] = (short)a.y; r[2] = (short)a.z; r[3] = (short)a.w;
    r[4] = (short)b.x; r[5] = (short)b.y; r[6] = (short)b.z; r[7] = (short)b.w;
    return r;
}

// bijective XCD-chunking swizzle (m204): consecutive work-items land on one XCD
__device__ __forceinline__ int xcd_swizzle(int orig, int T) {
    int q = T >> 3, r = T & 7;
    int xcd = orig & 7, idx = orig >> 3;
    return (xcd < r ? xcd * (q + 1) : r * (q + 1) + (xcd - r) * q) + idx;
}

// ---------------- K1: qkv = x @ Wqkv + b  (M x 384) @ (384 x 1152) -> bf16 ----
__global__ __launch_bounds__(256) void k_qkv(const float* __restrict__ x,
        const float* __restrict__ w, const float* __restrict__ bias,
        unsigned short* __restrict__ qkv, int m_base, int mt_total)
{
    __shared__ unsigned short As[64][44];   // [m][k], stride 44 -> conflict-free frags
    __shared__ unsigned short Bs[64][44];   // transposed [n][k]
    const int wg = xcd_swizzle(blockIdx.x, mt_total * 18);
    const int m0 = (wg / 18) * 64;          // chunk-local row base
    const int n0 = (wg % 18) * 64;
    const int tid = threadIdx.x;
    const int lane = tid & 63, wid = tid >> 6;
    const int wm = (wid >> 1) * 32, wn = (wid & 1) * 32;
    const int l15 = lane & 15, g = lane >> 4;

    f32x4 acc[2][2];
#pragma unroll
    for (int a = 0; a < 2; ++a)
#pragma unroll
        for (int b = 0; b < 2; ++b) acc[a][b] = (f32x4){0.f, 0.f, 0.f, 0.f};

    const int ar = tid >> 2, ac = (tid & 3) * 8;
    const int br = tid >> 3, bc = (tid & 7) * 8;
    const float* xp = x + (size_t)(m_base + m0 + ar) * CH + ac;
    const float* wp = w + (size_t)br * QKV_N + n0 + bc;

    for (int kt = 0; kt < 12; ++kt) {
        float4 a0 = *(const float4*)(xp);
        float4 a1 = *(const float4*)(xp + 4);
        float4 b0 = *(const float4*)(wp);
        float4 b1 = *(const float4*)(wp + 4);
        xp += 32; wp += (size_t)32 * QKV_N;
        unsigned int* ad = (unsigned int*)&As[ar][ac];
        ad[0] = (unsigned)f2b(a0.x) | ((unsigned)f2b(a0.y) << 16);
        ad[1] = (unsigned)f2b(a0.z) | ((unsigned)f2b(a0.w) << 16);
        ad[2] = (unsigned)f2b(a1.x) | ((unsigned)f2b(a1.y) << 16);
        ad[3] = (unsigned)f2b(a1.z) | ((unsigned)f2b(a1.w) << 16);
        Bs[bc + 0][br] = f2b(b0.x); Bs[bc + 1][br] = f2b(b0.y);
        Bs[bc + 2][br] = f2b(b0.z); Bs[bc + 3][br] = f2b(b0.w);
        Bs[bc + 4][br] = f2b(b1.x); Bs[bc + 5][br] = f2b(b1.y);
        Bs[bc + 6][br] = f2b(b1.z); Bs[bc + 7][br] = f2b(b1.w);
        __syncthreads();
        bf16x8 af[2], bfr[2];
#pragma unroll
        for (int mt = 0; mt < 2; ++mt) af[mt]  = ld8(&As[wm + mt * 16 + l15][g * 8]);
#pragma unroll
        for (int nt = 0; nt < 2; ++nt) bfr[nt] = ld8(&Bs[wn + nt * 16 + l15][g * 8]);
#pragma unroll
        for (int mt = 0; mt < 2; ++mt)
#pragma unroll
            for (int nt = 0; nt < 2; ++nt)
                acc[mt][nt] = __builtin_amdgcn_mfma_f32_16x16x32_bf16(
                        af[mt], bfr[nt], acc[mt][nt], 0, 0, 0);
        __syncthreads();
    }
#pragma unroll
    for (int mt = 0; mt < 2; ++mt)
#pragma unroll
        for (int nt = 0; nt < 2; ++nt) {
            int col = n0 + wn + nt * 16 + l15;
            float bb = bias[col];
#pragma unroll
            for (int r = 0; r < 4; ++r) {
                int row = m0 + wm + mt * 16 + g * 4 + r;
                qkv[(size_t)row * QKV_N + col] = f2b(acc[mt][nt][r] + bb);
            }
        }
}

// ---------------- K2: per-window attention ----------------------------------
__global__ __launch_bounds__(256) void k_attn(unsigned short* __restrict__ qkv,
        const float* __restrict__ mask, const float* __restrict__ btab, int win_base)
{
    extern __shared__ unsigned short sm[];
    unsigned short* qs = sm;                         // [49][1160] window qkv (bf16)
    const int bloc = blockIdx.x;
    const int tid = threadIdx.x;
    const int lane = tid & 63, wv = tid >> 6;
    const int l15 = lane & 15, g = lane >> 4;
    const int wimg = (win_base + bloc) & 63;
    unsigned short* Pw = sm + 49 * 1160 + wv * 64 * 72;   // per-wave P [64][72]

    unsigned short* src = qkv + (size_t)bloc * SEQ_N * QKV_N;
    for (int t = tid; t < SEQ_N * 144; t += 256) {
        int row = t / 144, cb = (t - row * 144) * 8;
        *(uint4*)(qs + row * 1160 + cb) = *(const uint4*)(src + (size_t)row * QKV_N + cb);
    }
    __syncthreads();

    int jj[4], jh[4], jw4[4];
#pragma unroll
    for (int nt = 0; nt < 4; ++nt) {
        int j = nt * 16 + l15;
        jj[nt] = j; jh[nt] = j / 7; jw4[nt] = j - (j / 7) * 7;
    }
    const float scale = 0.17677669529663687f;   // 32^-0.5

    for (int hi = 0; hi < 3; ++hi) {
        int h = hi * 4 + wv;
        int co = h * HDIM;
        // ---- S = q @ k^T  (A = q rows, B = k rows read k-contiguously)
        bf16x8 qf[4], kf[4];
#pragma unroll
        for (int mt = 0; mt < 4; ++mt) qf[mt] = ld8(qs + (mt * 16 + l15) * 1160 + co + g * 8);
#pragma unroll
        for (int nt = 0; nt < 4; ++nt) kf[nt] = ld8(qs + (nt * 16 + l15) * 1160 + 384 + co + g * 8);
        f32x4 sa[4][4];
#pragma unroll
        for (int mt = 0; mt < 4; ++mt)
#pragma unroll
            for (int nt = 0; nt < 4; ++nt) sa[mt][nt] = (f32x4){0.f, 0.f, 0.f, 0.f};
#pragma unroll
        for (int mt = 0; mt < 4; ++mt)
#pragma unroll
            for (int nt = 0; nt < 4; ++nt)
                sa[mt][nt] = __builtin_amdgcn_mfma_f32_16x16x32_bf16(
                        qf[mt], kf[nt], sa[mt][nt], 0, 0, 0);

        // ---- scale + rel-pos-bias + shift-mask, row softmax, P -> LDS (bf16)
#pragma unroll
        for (int mt = 0; mt < 4; ++mt) {
#pragma unroll
            for (int r = 0; r < 4; ++r) {
                int i = mt * 16 + g * 4 + r;
                int ic = i < 49 ? i : 48;              // clamp for pad rows
                int ih = ic / 7, iw = ic - (ic / 7) * 7;
                const float* mrow = mask + (size_t)wimg * 2401 + ic * 49;
                float sv[4];
#pragma unroll
                for (int nt = 0; nt < 4; ++nt) {
                    float s = sa[mt][nt][r];
                    if (jj[nt] < 49) {
                        int idx = (ih - jh[nt] + 6) * 13 + (iw - jw4[nt] + 6);
                        s = s * scale + btab[idx * 12 + h] + mrow[jj[nt]];
                    } else s = -1e30f;
                    sv[nt] = s;
                }
                float mx = fmaxf(fmaxf(sv[0], sv[1]), fmaxf(sv[2], sv[3]));
#pragma unroll
                for (int d = 1; d < 16; d <<= 1) mx = fmaxf(mx, __shfl_xor(mx, d));
                float sum = 0.f;
#pragma unroll
                for (int nt = 0; nt < 4; ++nt) { sv[nt] = __expf(sv[nt] - mx); sum += sv[nt]; }
#pragma unroll
                for (int d = 1; d < 16; d <<= 1) sum += __shfl_xor(sum, d);
                float inv = 1.0f / sum;
#pragma unroll
                for (int nt = 0; nt < 4; ++nt)
                    Pw[i * 72 + nt * 16 + l15] = f2b(sv[nt] * inv);
            }
        }
        __syncthreads();   // P visible to all lanes of each wave

        // ---- O = P @ V
        f32x4 oa[4][2];
#pragma unroll
        for (int mt = 0; mt < 4; ++mt)
#pragma unroll
            for (int nt = 0; nt < 2; ++nt) oa[mt][nt] = (f32x4){0.f, 0.f, 0.f, 0.f};
#pragma unroll
        for (int ks = 0; ks < 2; ++ks) {
            bf16x8 pf[4];
#pragma unroll
            for (int mt = 0; mt < 4; ++mt)
                pf[mt] = ld8(Pw + (mt * 16 + l15) * 72 + ks * 32 + g * 8);
#pragma unroll
            for (int nt = 0; nt < 2; ++nt) {
                bf16x8 vf;
#pragma unroll
                for (int jx = 0; jx < 8; ++jx) {
                    int kk = ks * 32 + g * 8 + jx;
                    vf[jx] = (kk < 49) ? (short)qs[kk * 1160 + 768 + co + nt * 16 + l15]
                                       : (short)0;
                }
#pragma unroll
                for (int mt = 0; mt < 4; ++mt)
                    oa[mt][nt] = __builtin_amdgcn_mfma_f32_16x16x32_bf16(
                            pf[mt], vf, oa[mt][nt], 0, 0, 0);
            }
        }
        // ---- write O into the q-columns of ws (head h -> cols h*32..)
#pragma unroll
        for (int mt = 0; mt < 4; ++mt)
#pragma unroll
            for (int r = 0; r < 4; ++r) {
                int i = mt * 16 + g * 4 + r;
                if (i < 49) {
#pragma unroll
                    for (int nt = 0; nt < 2; ++nt)
                        src[(size_t)i * QKV_N + co + nt * 16 + l15] = f2b(oa[mt][nt][r]);
                }
            }
        __syncthreads();   // protect Pw reuse next head
    }
}

// ---------------- K3: out = O @ Wproj + b  (M x 384) @ (384 x 384) -> fp32 ---
__global__ __launch_bounds__(256) void k_proj(const unsigned short* __restrict__ ain,
        const float* __restrict__ w, const float* __restrict__ bias,
        float* __restrict__ out, int m_base, int mt_total)
{
    __shared__ unsigned short As[64][44];
    __shared__ unsigned short Bs[64][44];   // transposed [n][k]
    const int wg = xcd_swizzle(blockIdx.x, mt_total * 6);
    const int m0 = (wg / 6) * 64;
    const int n0 = (wg % 6) * 64;
    const int tid = threadIdx.x;
    const int lane = tid & 63, wid = tid >> 6;
    const int wm = (wid >> 1) * 32, wn = (wid & 1) * 32;
    const int l15 = lane & 15, g = lane >> 4;

    f32x4 acc[2][2];
#pragma unroll
    for (int a = 0; a < 2; ++a)
#pragma unroll
        for (int b = 0; b < 2; ++b) acc[a][b] = (f32x4){0.f, 0.f, 0.f, 0.f};

    const int ar = tid >> 2, ac = (tid & 3) * 8;
    const int br = tid >> 3, bc = (tid & 7) * 8;
    const unsigned short* apg = ain + (size_t)(m0 + ar) * QKV_N + ac; // O lives in cols 0..383
    const float* wp = w + (size_t)br * CH + n0 + bc;

    for (int kt = 0; kt < 12; ++kt) {
        uint4 av = *(const uint4*)apg;
        float4 b0 = *(const float4*)(wp);
        float4 b1 = *(const float4*)(wp + 4);
        apg += 32; wp += (size_t)32 * CH;
        uint2* ad = (uint2*)&As[ar][ac];
        ad[0] = make_uint2(av.x, av.y);
        ad[1] = make_uint2(av.z, av.w);
        Bs[bc + 0][br] = f2b(b0.x); Bs[bc + 1][br] = f2b(b0.y);
        Bs[bc + 2][br] = f2b(b0.z); Bs[bc + 3][br] = f2b(b0.w);
        Bs[bc + 4][br] = f2b(b1.x); Bs[bc + 5][br] = f2b(b1.y);
        Bs[bc + 6][br] = f2b(b1.z); Bs[bc + 7][br] = f2b(b1.w);
        __syncthreads();
        bf16x8 af[2], bfr[2];
#pragma unroll
        for (int mt = 0; mt < 2; ++mt) af[mt]  = ld8(&As[wm + mt * 16 + l15][g * 8]);
#pragma unroll
        for (int nt = 0; nt < 2; ++nt) bfr[nt] = ld8(&Bs[wn + nt * 16 + l15][g * 8]);
#pragma unroll
        for (int mt = 0; mt < 2; ++mt)
#pragma unroll
            for (int nt = 0; nt < 2; ++nt)
                acc[mt][nt] = __builtin_amdgcn_mfma_f32_16x16x32_bf16(
                        af[mt], bfr[nt], acc[mt][nt], 0, 0, 0);
        __syncthreads();
    }
#pragma unroll
    for (int mt = 0; mt < 2; ++mt)
#pragma unroll
        for (int nt = 0; nt < 2; ++nt) {
            int col = n0 + wn + nt * 16 + l15;
            float bb = bias[col];
#pragma unroll
            for (int r = 0; r < 4; ++r) {
                int row = m0 + wm + mt * 16 + g * 4 + r;
                out[(size_t)(m_base + row) * CH + col] = acc[mt][nt][r] + bb;
            }
        }
}

extern "C" void kernel_launch(void* const* d_in, const int* in_sizes, int n_in,
                              void* d_out, int out_size, void* d_ws, size_t ws_size,
                              hipStream_t stream) {
    const float* x      = (const float*)d_in[0];
    const float* mask   = (const float*)d_in[1];
    const float* qkv_w  = (const float*)d_in[2];
    const float* qkv_b  = (const float*)d_in[3];
    const float* proj_w = (const float*)d_in[4];
    const float* proj_b = (const float*)d_in[5];
    const float* btab   = (const float*)d_in[6];
    float* out = (float*)d_out;
    unsigned short* qkv = (unsigned short*)d_ws;

    const size_t unit_bytes = (size_t)UNIT_ROWS * QKV_N * 2;  // 7,225,344 B
    if (ws_size < unit_bytes) return;  // need >= 7.3 MB scratch
    int upc = (int)(ws_size / unit_bytes);
    if (upc > 64) upc = 64;

    const size_t smem2 = (size_t)(49 * 1160 + 4 * 64 * 72) * 2;  // 150,544 B
    hipFuncSetAttribute(reinterpret_cast<const void*>(k_attn),
                        hipFuncAttributeMaxDynamicSharedMemorySize, (int)smem2);

    dim3 blk(256);
    for (int u0 = 0; u0 < 64; u0 += upc) {
        int units = (64 - u0) < upc ? (64 - u0) : upc;
        int m_base = u0 * UNIT_ROWS;
        int win_base = u0 * UNIT_WIN;
        int mt = units * 49;   // 64-row tiles in this chunk
        k_qkv <<<dim3(mt * 18), blk, 0, stream>>>(x, qkv_w, qkv_b, qkv, m_base, mt);
        k_attn<<<dim3(units * UNIT_WIN), blk, smem2, stream>>>(qkv, mask, btab, win_base);
        k_proj<<<dim3(mt * 6), blk, 0, stream>>>(qkv, proj_w, proj_b, out, m_base, mt);
    }
}

// Round 2
// 1200.749 us; speedup vs baseline: 1.2542x; 1.2542x over previous
//
#include <hip/hip_runtime.h>
#include <hip/hip_bf16.h>

// WindowAttention (Swin) on MI355X — round 2
//   K1 k_qkv : qkv = x @ Wqkv + b   (bf16 MFMA 64x64 tiles) -> ws (bf16)
//   K2 k_attn: REWRITTEN — 1 wave per (window, head), q/k frags direct from
//              global, wave-private LDS only for V^T and P (55.3 KB/block ->
//              2 blocks/CU vs 1 before). O written into q-columns of ws.
//   K3 k_proj: out = O @ Wproj + b  (fp32 output)

typedef __attribute__((ext_vector_type(8))) short bf16x8;
typedef __attribute__((ext_vector_type(4))) float f32x4;

#define SEQ_N  49
#define CH     384
#define QKV_N  1152
#define HDIM   32
#define UNIT_WIN  64
#define UNIT_ROWS 3136   // 64 windows * 49 rows

__device__ __forceinline__ unsigned short f2b(float f) {
    union { float f; unsigned int u; } v; v.f = f;
    return (unsigned short)((v.u + 0x7FFFu + ((v.u >> 16) & 1u)) >> 16);
}

__device__ __forceinline__ bf16x8 ld8(const unsigned short* p) {
    const ushort4* p4 = (const ushort4*)p;   // 16B-aligned at every call site
    ushort4 a = p4[0], b = p4[1];
    bf16x8 r;
    r[0] = (short)a.x; r[1] = (short)a.y; r[2] = (short)a.z; r[3] = (short)a.w;
    r[4] = (short)b.x; r[5] = (short)b.y; r[6] = (short)b.z; r[7] = (short)b.w;
    return r;
}

// bijective XCD-chunking swizzle (m204)
__device__ __forceinline__ int xcd_swizzle(int orig, int T) {
    int q = T >> 3, r = T & 7;
    int xcd = orig & 7, idx = orig >> 3;
    return (xcd < r ? xcd * (q + 1) : r * (q + 1) + (xcd - r) * q) + idx;
}

// ---------------- K1: qkv = x @ Wqkv + b  (M x 384) @ (384 x 1152) -> bf16 ----
__global__ __launch_bounds__(256) void k_qkv(const float* __restrict__ x,
        const float* __restrict__ w, const float* __restrict__ bias,
        unsigned short* __restrict__ qkv, int m_base, int mt_total)
{
    __shared__ unsigned short As[64][44];
    __shared__ unsigned short Bs[64][44];
    const int wg = xcd_swizzle(blockIdx.x, mt_total * 18);
    const int m0 = (wg / 18) * 64;
    const int n0 = (wg % 18) * 64;
    const int tid = threadIdx.x;
    const int lane = tid & 63, wid = tid >> 6;
    const int wm = (wid >> 1) * 32, wn = (wid & 1) * 32;
    const int l15 = lane & 15, g = lane >> 4;

    f32x4 acc[2][2];
#pragma unroll
    for (int a = 0; a < 2; ++a)
#pragma unroll
        for (int b = 0; b < 2; ++b) acc[a][b] = (f32x4){0.f, 0.f, 0.f, 0.f};

    const int ar = tid >> 2, ac = (tid & 3) * 8;
    const int br = tid >> 3, bc = (tid & 7) * 8;
    const float* xp = x + (size_t)(m_base + m0 + ar) * CH + ac;
    const float* wp = w + (size_t)br * QKV_N + n0 + bc;

    for (int kt = 0; kt < 12; ++kt) {
        float4 a0 = *(const float4*)(xp);
        float4 a1 = *(const float4*)(xp + 4);
        float4 b0 = *(const float4*)(wp);
        float4 b1 = *(const float4*)(wp + 4);
        xp += 32; wp += (size_t)32 * QKV_N;
        unsigned int* ad = (unsigned int*)&As[ar][ac];
        ad[0] = (unsigned)f2b(a0.x) | ((unsigned)f2b(a0.y) << 16);
        ad[1] = (unsigned)f2b(a0.z) | ((unsigned)f2b(a0.w) << 16);
        ad[2] = (unsigned)f2b(a1.x) | ((unsigned)f2b(a1.y) << 16);
        ad[3] = (unsigned)f2b(a1.z) | ((unsigned)f2b(a1.w) << 16);
        Bs[bc + 0][br] = f2b(b0.x); Bs[bc + 1][br] = f2b(b0.y);
        Bs[bc + 2][br] = f2b(b0.z); Bs[bc + 3][br] = f2b(b0.w);
        Bs[bc + 4][br] = f2b(b1.x); Bs[bc + 5][br] = f2b(b1.y);
        Bs[bc + 6][br] = f2b(b1.z); Bs[bc + 7][br] = f2b(b1.w);
        __syncthreads();
        bf16x8 af[2], bfr[2];
#pragma unroll
        for (int mt = 0; mt < 2; ++mt) af[mt]  = ld8(&As[wm + mt * 16 + l15][g * 8]);
#pragma unroll
        for (int nt = 0; nt < 2; ++nt) bfr[nt] = ld8(&Bs[wn + nt * 16 + l15][g * 8]);
#pragma unroll
        for (int mt = 0; mt < 2; ++mt)
#pragma unroll
            for (int nt = 0; nt < 2; ++nt)
                acc[mt][nt] = __builtin_amdgcn_mfma_f32_16x16x32_bf16(
                        af[mt], bfr[nt], acc[mt][nt], 0, 0, 0);
        __syncthreads();
    }
#pragma unroll
    for (int mt = 0; mt < 2; ++mt)
#pragma unroll
        for (int nt = 0; nt < 2; ++nt) {
            int col = n0 + wn + nt * 16 + l15;
            float bb = bias[col];
#pragma unroll
            for (int r = 0; r < 4; ++r) {
                int row = m0 + wm + mt * 16 + g * 4 + r;
                qkv[(size_t)row * QKV_N + col] = f2b(acc[mt][nt][r] + bb);
            }
        }
}

// ---------------- K2: attention, 1 wave per (window, head) -------------------
__global__ __launch_bounds__(256) void k_attn(unsigned short* __restrict__ qkv,
        const float* __restrict__ mask, const float* __restrict__ btab, int win_base)
{
    extern __shared__ unsigned short sm[];
    const int tid = threadIdx.x;
    const int lane = tid & 63, wv = tid >> 6;
    const int l15 = lane & 15, g = lane >> 4;
    const int pair = blockIdx.x * 4 + wv;
    const int winloc = pair / 12;
    const int h = pair - winloc * 12;
    const int wimg = (win_base + winloc) & 63;
    const int co = h * HDIM;
    unsigned short* Vt = sm + wv * 6912;     // [32][72]  V^T (col, k) pad-72
    unsigned short* Pw = Vt + 32 * 72;       // [64][72]  P  (row, k) pad-72
    unsigned short* src = qkv + (size_t)winloc * SEQ_N * QKV_N;

    // ---- stage V^T: Vt[col][k], zero the k=48..63 pad
    for (int t = lane; t < 32 * 16; t += 64) {
        int c = t >> 4, kk = 48 + (t & 15);
        Vt[c * 72 + kk] = 0;
    }
    for (int t = lane; t < 49 * 4; t += 64) {
        int row = t >> 2, cb = (t & 3) * 8;
        const unsigned short* vp = src + (size_t)row * QKV_N + 768 + co + cb;
        ushort4 a = ((const ushort4*)vp)[0];
        ushort4 b = ((const ushort4*)vp)[1];
        Vt[(cb + 0) * 72 + row] = a.x; Vt[(cb + 1) * 72 + row] = a.y;
        Vt[(cb + 2) * 72 + row] = a.z; Vt[(cb + 3) * 72 + row] = a.w;
        Vt[(cb + 4) * 72 + row] = b.x; Vt[(cb + 5) * 72 + row] = b.y;
        Vt[(cb + 6) * 72 + row] = b.z; Vt[(cb + 7) * 72 + row] = b.w;
    }

    // ---- q,k fragments straight from global (rows >=49 clamped; masked later)
    bf16x8 qf[4], kf[4];
#pragma unroll
    for (int mt = 0; mt < 4; ++mt) {
        int r = mt * 16 + l15; if (r > 48) r = 48;
        qf[mt] = ld8(src + (size_t)r * QKV_N + co + g * 8);
    }
#pragma unroll
    for (int nt = 0; nt < 4; ++nt) {
        int r = nt * 16 + l15; if (r > 48) r = 48;
        kf[nt] = ld8(src + (size_t)r * QKV_N + CH + co + g * 8);
    }

    // ---- S = q @ k^T
    f32x4 sa[4][4];
#pragma unroll
    for (int mt = 0; mt < 4; ++mt)
#pragma unroll
        for (int nt = 0; nt < 4; ++nt) sa[mt][nt] = (f32x4){0.f, 0.f, 0.f, 0.f};
#pragma unroll
    for (int mt = 0; mt < 4; ++mt)
#pragma unroll
        for (int nt = 0; nt < 4; ++nt)
            sa[mt][nt] = __builtin_amdgcn_mfma_f32_16x16x32_bf16(
                    qf[mt], kf[nt], sa[mt][nt], 0, 0, 0);

    // ---- scale + bias + mask + row softmax -> P (bf16, LDS)
    int jj[4], jh[4], jw4[4];
#pragma unroll
    for (int nt = 0; nt < 4; ++nt) {
        int j = nt * 16 + l15;
        jj[nt] = j; jh[nt] = j / 7; jw4[nt] = j - (j / 7) * 7;
    }
    const float scale = 0.17677669529663687f;   // 32^-0.5
#pragma unroll
    for (int mt = 0; mt < 4; ++mt) {
#pragma unroll
        for (int r = 0; r < 4; ++r) {
            int i = mt * 16 + g * 4 + r;
            int ic = i < 49 ? i : 48;
            int ih = ic / 7, iw = ic - (ic / 7) * 7;
            const float* mrow = mask + (size_t)wimg * 2401 + ic * 49;
            float sv[4];
#pragma unroll
            for (int nt = 0; nt < 4; ++nt) {
                float s = sa[mt][nt][r];
                if (jj[nt] < 49) {
                    int idx = (ih - jh[nt] + 6) * 13 + (iw - jw4[nt] + 6);
                    s = s * scale + btab[idx * 12 + h] + mrow[jj[nt]];
                } else s = -1e30f;
                sv[nt] = s;
            }
            float mx = fmaxf(fmaxf(sv[0], sv[1]), fmaxf(sv[2], sv[3]));
#pragma unroll
            for (int d = 1; d < 16; d <<= 1) mx = fmaxf(mx, __shfl_xor(mx, d));
            float sum = 0.f;
#pragma unroll
            for (int nt = 0; nt < 4; ++nt) { sv[nt] = __expf(sv[nt] - mx); sum += sv[nt]; }
#pragma unroll
            for (int d = 1; d < 16; d <<= 1) sum += __shfl_xor(sum, d);
            float inv = 1.0f / sum;
#pragma unroll
            for (int nt = 0; nt < 4; ++nt)
                Pw[i * 72 + nt * 16 + l15] = f2b(sv[nt] * inv);
        }
    }
    __syncthreads();   // (uniform flow; orders wave-private LDS phases)

    // ---- O = P @ V
    f32x4 oa[4][2];
#pragma unroll
    for (int mt = 0; mt < 4; ++mt)
#pragma unroll
        for (int nt = 0; nt < 2; ++nt) oa[mt][nt] = (f32x4){0.f, 0.f, 0.f, 0.f};
#pragma unroll
    for (int ks = 0; ks < 2; ++ks) {
        bf16x8 pf[4];
#pragma unroll
        for (int mt = 0; mt < 4; ++mt)
            pf[mt] = ld8(Pw + (mt * 16 + l15) * 72 + ks * 32 + g * 8);
#pragma unroll
        for (int nt = 0; nt < 2; ++nt) {
            bf16x8 vf = ld8(Vt + (nt * 16 + l15) * 72 + ks * 32 + g * 8);
#pragma unroll
            for (int mt = 0; mt < 4; ++mt)
                oa[mt][nt] = __builtin_amdgcn_mfma_f32_16x16x32_bf16(
                        pf[mt], vf, oa[mt][nt], 0, 0, 0);
        }
    }

    // ---- O -> q-columns of ws
#pragma unroll
    for (int mt = 0; mt < 4; ++mt)
#pragma unroll
        for (int r = 0; r < 4; ++r) {
            int i = mt * 16 + g * 4 + r;
            if (i < 49) {
#pragma unroll
                for (int nt = 0; nt < 2; ++nt)
                    src[(size_t)i * QKV_N + co + nt * 16 + l15] = f2b(oa[mt][nt][r]);
            }
        }
}

// ---------------- K3: out = O @ Wproj + b  (M x 384) @ (384 x 384) -> fp32 ---
__global__ __launch_bounds__(256) void k_proj(const unsigned short* __restrict__ ain,
        const float* __restrict__ w, const float* __restrict__ bias,
        float* __restrict__ out, int m_base, int mt_total)
{
    __shared__ unsigned short As[64][44];
    __shared__ unsigned short Bs[64][44];
    const int wg = xcd_swizzle(blockIdx.x, mt_total * 6);
    const int m0 = (wg / 6) * 64;
    const int n0 = (wg % 6) * 64;
    const int tid = threadIdx.x;
    const int lane = tid & 63, wid = tid >> 6;
    const int wm = (wid >> 1) * 32, wn = (wid & 1) * 32;
    const int l15 = lane & 15, g = lane >> 4;

    f32x4 acc[2][2];
#pragma unroll
    for (int a = 0; a < 2; ++a)
#pragma unroll
        for (int b = 0; b < 2; ++b) acc[a][b] = (f32x4){0.f, 0.f, 0.f, 0.f};

    const int ar = tid >> 2, ac = (tid & 3) * 8;
    const int br = tid >> 3, bc = (tid & 7) * 8;
    const unsigned short* apg = ain + (size_t)(m0 + ar) * QKV_N + ac;
    const float* wp = w + (size_t)br * CH + n0 + bc;

    for (int kt = 0; kt < 12; ++kt) {
        uint4 av = *(const uint4*)apg;
        float4 b0 = *(const float4*)(wp);
        float4 b1 = *(const float4*)(wp + 4);
        apg += 32; wp += (size_t)32 * CH;
        uint2* ad = (uint2*)&As[ar][ac];
        ad[0] = make_uint2(av.x, av.y);
        ad[1] = make_uint2(av.z, av.w);
        Bs[bc + 0][br] = f2b(b0.x); Bs[bc + 1][br] = f2b(b0.y);
        Bs[bc + 2][br] = f2b(b0.z); Bs[bc + 3][br] = f2b(b0.w);
        Bs[bc + 4][br] = f2b(b1.x); Bs[bc + 5][br] = f2b(b1.y);
        Bs[bc + 6][br] = f2b(b1.z); Bs[bc + 7][br] = f2b(b1.w);
        __syncthreads();
        bf16x8 af[2], bfr[2];
#pragma unroll
        for (int mt = 0; mt < 2; ++mt) af[mt]  = ld8(&As[wm + mt * 16 + l15][g * 8]);
#pragma unroll
        for (int nt = 0; nt < 2; ++nt) bfr[nt] = ld8(&Bs[wn + nt * 16 + l15][g * 8]);
#pragma unroll
        for (int mt = 0; mt < 2; ++mt)
#pragma unroll
            for (int nt = 0; nt < 2; ++nt)
                acc[mt][nt] = __builtin_amdgcn_mfma_f32_16x16x32_bf16(
                        af[mt], bfr[nt], acc[mt][nt], 0, 0, 0);
        __syncthreads();
    }
#pragma unroll
    for (int mt = 0; mt < 2; ++mt)
#pragma unroll
        for (int nt = 0; nt < 2; ++nt) {
            int col = n0 + wn + nt * 16 + l15;
            float bb = bias[col];
#pragma unroll
            for (int r = 0; r < 4; ++r) {
                int row = m0 + wm + mt * 16 + g * 4 + r;
                out[(size_t)(m_base + row) * CH + col] = acc[mt][nt][r] + bb;
            }
        }
}

extern "C" void kernel_launch(void* const* d_in, const int* in_sizes, int n_in,
                              void* d_out, int out_size, void* d_ws, size_t ws_size,
                              hipStream_t stream) {
    const float* x      = (const float*)d_in[0];
    const float* mask   = (const float*)d_in[1];
    const float* qkv_w  = (const float*)d_in[2];
    const float* qkv_b  = (const float*)d_in[3];
    const float* proj_w = (const float*)d_in[4];
    const float* proj_b = (const float*)d_in[5];
    const float* btab   = (const float*)d_in[6];
    float* out = (float*)d_out;
    unsigned short* qkv = (unsigned short*)d_ws;

    const size_t unit_bytes = (size_t)UNIT_ROWS * QKV_N * 2;  // 7,225,344 B
    if (ws_size < unit_bytes) return;
    int upc = (int)(ws_size / unit_bytes);
    if (upc > 64) upc = 64;

    const int smem2 = 4 * 6912 * 2;   // 55,296 B -> 2 blocks/CU
    hipFuncSetAttribute(reinterpret_cast<const void*>(k_attn),
                        hipFuncAttributeMaxDynamicSharedMemorySize, smem2);

    dim3 blk(256);
    for (int u0 = 0; u0 < 64; u0 += upc) {
        int units = (64 - u0) < upc ? (64 - u0) : upc;
        int m_base = u0 * UNIT_ROWS;
        int win_base = u0 * UNIT_WIN;
        int mt = units * 49;
        k_qkv <<<dim3(mt * 18), blk, 0, stream>>>(x, qkv_w, qkv_b, qkv, m_base, mt);
        k_attn<<<dim3(units * 192), blk, smem2, stream>>>(qkv, mask, btab, win_base);
        k_proj<<<dim3(mt * 6), blk, 0, stream>>>(qkv, proj_w, proj_b, out, m_base, mt);
    }
}

// Round 3
// 1049.778 us; speedup vs baseline: 1.4345x; 1.1438x over previous
//
#include <hip/hip_runtime.h>
#include <hip/hip_bf16.h>

// WindowAttention (Swin) on MI355X — round 3
//   k_cvt_w : qkv_w/proj_w fp32 -> bf16 B^T (n-major) [once per launch]
//   k_cvt   : x fp32 -> bf16 (each element converted exactly once)
//   k_gemm  : m97-structure 128x128xBK32 bf16 GEMM, global_load_lds(16B)
//             staging, 4 waves, 4x4 16x16x32 acc. Used for qkv (bf16 out)
//             and proj (fp32 out + bias).
//   k_attn  : unchanged from round 2 (1 wave per (window,head)).

typedef __attribute__((ext_vector_type(8))) short bf16x8;
typedef __attribute__((ext_vector_type(4))) float f32x4;

#define SEQ_N  49
#define CH     384
#define QKV_N  1152
#define HDIM   32
#define UNIT_ROWS 3136   // 64 windows * 49 rows

__device__ __forceinline__ unsigned short f2b(float f) {
    union { float f; unsigned int u; } v; v.f = f;
    return (unsigned short)((v.u + 0x7FFFu + ((v.u >> 16) & 1u)) >> 16);
}

__device__ __forceinline__ bf16x8 ld8(const unsigned short* p) {
    return *(const bf16x8*)p;    // 16B-aligned at every call site
}

// async global->LDS, 16B per lane; lds dst must be wave-uniform base
__device__ __forceinline__ void gload16(const unsigned short* g, unsigned short* l) {
    __builtin_amdgcn_global_load_lds(
        (const __attribute__((address_space(1))) unsigned int*)g,
        (__attribute__((address_space(3))) unsigned int*)l, 16, 0, 0);
}

// bijective XCD-chunking swizzle (m204)
__device__ __forceinline__ int xcd_swizzle(int orig, int T) {
    int q = T >> 3, r = T & 7;
    int xcd = orig & 7, idx = orig >> 3;
    return (xcd < r ? xcd * (q + 1) : r * (q + 1) + (xcd - r) * q) + idx;
}

// ---------------- weight convert+transpose: Bt[n][k] = bf16(W[k][n]) --------
__global__ __launch_bounds__(256) void k_cvt_w(const float* __restrict__ wq,
        const float* __restrict__ wp, unsigned short* __restrict__ oq,
        unsigned short* __restrict__ op)
{
    int t = blockIdx.x * 256 + threadIdx.x;
    if (t < QKV_N * CH) {              // 442368
        int n = t / CH, k = t - n * CH;
        oq[t] = f2b(wq[(size_t)k * QKV_N + n]);
    }
    if (t < CH * CH) {                 // 147456
        int n = t / CH, k = t - n * CH;
        op[t] = f2b(wp[(size_t)k * CH + n]);
    }
}

// ---------------- x fp32 -> bf16 (vectorized, grid-stride) -------------------
__global__ __launch_bounds__(256) void k_cvt(const float* __restrict__ in,
        unsigned short* __restrict__ outp, int n8)
{
    int stride = gridDim.x * 256;
    for (int i = blockIdx.x * 256 + threadIdx.x; i < n8; i += stride) {
        const float4* p = (const float4*)(in + (size_t)i * 8);
        float4 a = p[0], b = p[1];
        uint4 v;
        v.x = (unsigned)f2b(a.x) | ((unsigned)f2b(a.y) << 16);
        v.y = (unsigned)f2b(a.z) | ((unsigned)f2b(a.w) << 16);
        v.z = (unsigned)f2b(b.x) | ((unsigned)f2b(b.y) << 16);
        v.w = (unsigned)f2b(b.z) | ((unsigned)f2b(b.w) << 16);
        *(uint4*)(outp + (size_t)i * 8) = v;
    }
}

// ---------------- m97-style GEMM: C[M][ldc] = A[M][lda] @ Bt^T + bias --------
// A bf16 row-major, Bt bf16 n-major [N][K]. OUTF32: fp32 C, else bf16 C.
template<int OUTF32>
__global__ __launch_bounds__(256) void k_gemm(
        const unsigned short* __restrict__ A, int lda,
        const unsigned short* __restrict__ Bt, int K,
        const float* __restrict__ bias,
        unsigned short* __restrict__ Cb, float* __restrict__ Cf, int ldc,
        int M, int ntiles, int mtiles)
{
    __shared__ unsigned short As[128 * 32];
    __shared__ unsigned short Bs[128 * 32];
    const int wg = xcd_swizzle(blockIdx.x, mtiles * ntiles);
    const int m0 = (wg / ntiles) * 128;
    const int n0 = (wg % ntiles) * 128;
    const int tid = threadIdx.x;
    const int lane = tid & 63, wid = tid >> 6;
    const int wm = (wid >> 1) * 64, wn = (wid & 1) * 64;
    const int l15 = lane & 15, g = lane >> 4;

    f32x4 acc[4][4];
#pragma unroll
    for (int a = 0; a < 4; ++a)
#pragma unroll
        for (int b = 0; b < 4; ++b) acc[a][b] = (f32x4){0.f, 0.f, 0.f, 0.f};

    // staging source: lane covers row r0 (+64 for 2nd issue), k elems kofs..+7
    const int r0 = wid * 16 + (lane >> 2);
    const int kofs = (lane & 3) * 8;
    int ra0 = m0 + r0;       if (ra0 > M - 1) ra0 = M - 1;
    int ra1 = m0 + 64 + r0;  if (ra1 > M - 1) ra1 = M - 1;
    const unsigned short* a0p = A + (size_t)ra0 * lda + kofs;
    const unsigned short* a1p = A + (size_t)ra1 * lda + kofs;
    const unsigned short* b0p = Bt + (size_t)(n0 + r0) * K + kofs;
    const unsigned short* b1p = Bt + (size_t)(n0 + 64 + r0) * K + kofs;
    unsigned short* la0 = As + wid * 512;          // wave-uniform LDS bases
    unsigned short* la1 = As + 2048 + wid * 512;
    unsigned short* lb0 = Bs + wid * 512;
    unsigned short* lb1 = Bs + 2048 + wid * 512;

    for (int kt = 0; kt < K; kt += 32) {
        gload16(a0p, la0);
        gload16(a1p, la1);
        gload16(b0p, lb0);
        gload16(b1p, lb1);
        a0p += 32; a1p += 32; b0p += 32; b1p += 32;
        __syncthreads();                 // drains vmcnt -> tiles ready
        bf16x8 af[4], bfr[4];
#pragma unroll
        for (int mt = 0; mt < 4; ++mt)
            af[mt] = ld8(&As[(wm + mt * 16 + l15) * 32 + g * 8]);
#pragma unroll
        for (int nt = 0; nt < 4; ++nt)
            bfr[nt] = ld8(&Bs[(wn + nt * 16 + l15) * 32 + g * 8]);
#pragma unroll
        for (int mt = 0; mt < 4; ++mt)
#pragma unroll
            for (int nt = 0; nt < 4; ++nt)
                acc[mt][nt] = __builtin_amdgcn_mfma_f32_16x16x32_bf16(
                        af[mt], bfr[nt], acc[mt][nt], 0, 0, 0);
        __syncthreads();                 // all reads done before re-stage
    }

#pragma unroll
    for (int mt = 0; mt < 4; ++mt)
#pragma unroll
        for (int nt = 0; nt < 4; ++nt) {
            int col = n0 + wn + nt * 16 + l15;
            float bb = bias[col];
#pragma unroll
            for (int r = 0; r < 4; ++r) {
                int row = m0 + wm + mt * 16 + g * 4 + r;
                if (row < M) {
                    if (OUTF32)
                        Cf[(size_t)row * ldc + col] = acc[mt][nt][r] + bb;
                    else
                        Cb[(size_t)row * ldc + col] = f2b(acc[mt][nt][r] + bb);
                }
            }
        }
}

// ---------------- attention: 1 wave per (window, head) -----------------------
__global__ __launch_bounds__(256) void k_attn(unsigned short* __restrict__ qkv,
        const float* __restrict__ mask, const float* __restrict__ btab, int win_base)
{
    extern __shared__ unsigned short sm[];
    const int tid = threadIdx.x;
    const int lane = tid & 63, wv = tid >> 6;
    const int l15 = lane & 15, g = lane >> 4;
    const int pair = blockIdx.x * 4 + wv;
    const int winloc = pair / 12;
    const int h = pair - winloc * 12;
    const int wimg = (win_base + winloc) & 63;
    const int co = h * HDIM;
    unsigned short* Vt = sm + wv * 6912;     // [32][72]  V^T
    unsigned short* Pw = Vt + 32 * 72;       // [64][72]  P
    unsigned short* src = qkv + (size_t)winloc * SEQ_N * QKV_N;

    for (int t = lane; t < 32 * 16; t += 64) {
        int c = t >> 4, kk = 48 + (t & 15);
        Vt[c * 72 + kk] = 0;
    }
    for (int t = lane; t < 49 * 4; t += 64) {
        int row = t >> 2, cb = (t & 3) * 8;
        const unsigned short* vp = src + (size_t)row * QKV_N + 768 + co + cb;
        ushort4 a = ((const ushort4*)vp)[0];
        ushort4 b = ((const ushort4*)vp)[1];
        Vt[(cb + 0) * 72 + row] = a.x; Vt[(cb + 1) * 72 + row] = a.y;
        Vt[(cb + 2) * 72 + row] = a.z; Vt[(cb + 3) * 72 + row] = a.w;
        Vt[(cb + 4) * 72 + row] = b.x; Vt[(cb + 5) * 72 + row] = b.y;
        Vt[(cb + 6) * 72 + row] = b.z; Vt[(cb + 7) * 72 + row] = b.w;
    }

    bf16x8 qf[4], kf[4];
#pragma unroll
    for (int mt = 0; mt < 4; ++mt) {
        int r = mt * 16 + l15; if (r > 48) r = 48;
        qf[mt] = ld8(src + (size_t)r * QKV_N + co + g * 8);
    }
#pragma unroll
    for (int nt = 0; nt < 4; ++nt) {
        int r = nt * 16 + l15; if (r > 48) r = 48;
        kf[nt] = ld8(src + (size_t)r * QKV_N + CH + co + g * 8);
    }

    f32x4 sa[4][4];
#pragma unroll
    for (int mt = 0; mt < 4; ++mt)
#pragma unroll
        for (int nt = 0; nt < 4; ++nt) sa[mt][nt] = (f32x4){0.f, 0.f, 0.f, 0.f};
#pragma unroll
    for (int mt = 0; mt < 4; ++mt)
#pragma unroll
        for (int nt = 0; nt < 4; ++nt)
            sa[mt][nt] = __builtin_amdgcn_mfma_f32_16x16x32_bf16(
                    qf[mt], kf[nt], sa[mt][nt], 0, 0, 0);

    int jj[4], jh[4], jw4[4];
#pragma unroll
    for (int nt = 0; nt < 4; ++nt) {
        int j = nt * 16 + l15;
        jj[nt] = j; jh[nt] = j / 7; jw4[nt] = j - (j / 7) * 7;
    }
    const float scale = 0.17677669529663687f;
#pragma unroll
    for (int mt = 0; mt < 4; ++mt) {
#pragma unroll
        for (int r = 0; r < 4; ++r) {
            int i = mt * 16 + g * 4 + r;
            int ic = i < 49 ? i : 48;
            int ih = ic / 7, iw = ic - (ic / 7) * 7;
            const float* mrow = mask + (size_t)wimg * 2401 + ic * 49;
            float sv[4];
#pragma unroll
            for (int nt = 0; nt < 4; ++nt) {
                float s = sa[mt][nt][r];
                if (jj[nt] < 49) {
                    int idx = (ih - jh[nt] + 6) * 13 + (iw - jw4[nt] + 6);
                    s = s * scale + btab[idx * 12 + h] + mrow[jj[nt]];
                } else s = -1e30f;
                sv[nt] = s;
            }
            float mx = fmaxf(fmaxf(sv[0], sv[1]), fmaxf(sv[2], sv[3]));
#pragma unroll
            for (int d = 1; d < 16; d <<= 1) mx = fmaxf(mx, __shfl_xor(mx, d));
            float sum = 0.f;
#pragma unroll
            for (int nt = 0; nt < 4; ++nt) { sv[nt] = __expf(sv[nt] - mx); sum += sv[nt]; }
#pragma unroll
            for (int d = 1; d < 16; d <<= 1) sum += __shfl_xor(sum, d);
            float inv = 1.0f / sum;
#pragma unroll
            for (int nt = 0; nt < 4; ++nt)
                Pw[i * 72 + nt * 16 + l15] = f2b(sv[nt] * inv);
        }
    }
    __syncthreads();

    f32x4 oa[4][2];
#pragma unroll
    for (int mt = 0; mt < 4; ++mt)
#pragma unroll
        for (int nt = 0; nt < 2; ++nt) oa[mt][nt] = (f32x4){0.f, 0.f, 0.f, 0.f};
#pragma unroll
    for (int ks = 0; ks < 2; ++ks) {
        bf16x8 pf[4];
#pragma unroll
        for (int mt = 0; mt < 4; ++mt)
            pf[mt] = ld8(Pw + (mt * 16 + l15) * 72 + ks * 32 + g * 8);
#pragma unroll
        for (int nt = 0; nt < 2; ++nt) {
            bf16x8 vf = ld8(Vt + (nt * 16 + l15) * 72 + ks * 32 + g * 8);
#pragma unroll
            for (int mt = 0; mt < 4; ++mt)
                oa[mt][nt] = __builtin_amdgcn_mfma_f32_16x16x32_bf16(
                        pf[mt], vf, oa[mt][nt], 0, 0, 0);
        }
    }

#pragma unroll
    for (int mt = 0; mt < 4; ++mt)
#pragma unroll
        for (int r = 0; r < 4; ++r) {
            int i = mt * 16 + g * 4 + r;
            if (i < 49) {
#pragma unroll
                for (int nt = 0; nt < 2; ++nt)
                    src[(size_t)i * QKV_N + co + nt * 16 + l15] = f2b(oa[mt][nt][r]);
            }
        }
}

extern "C" void kernel_launch(void* const* d_in, const int* in_sizes, int n_in,
                              void* d_out, int out_size, void* d_ws, size_t ws_size,
                              hipStream_t stream) {
    const float* x      = (const float*)d_in[0];
    const float* mask   = (const float*)d_in[1];
    const float* qkv_w  = (const float*)d_in[2];
    const float* qkv_b  = (const float*)d_in[3];
    const float* proj_w = (const float*)d_in[4];
    const float* proj_b = (const float*)d_in[5];
    const float* btab   = (const float*)d_in[6];
    float* out = (float*)d_out;

    // ws layout: [wq_bt][wp_bt][xb chunk][qkv chunk]
    unsigned short* wq_bt = (unsigned short*)d_ws;          // 442368 elems
    unsigned short* wp_bt = wq_bt + QKV_N * CH;             // 147456 elems
    unsigned short* base  = wp_bt + CH * CH;
    const size_t fixed = (size_t)(QKV_N * CH + CH * CH) * 2;           // 1,179,648 B
    const size_t unit  = (size_t)UNIT_ROWS * (CH + QKV_N) * 2;         // 9,633,792 B
    if (ws_size < fixed + unit) return;
    int upc = (int)((ws_size - fixed) / unit);
    if (upc > 64) upc = 64;
    unsigned short* xb  = base;                             // upc*3136*384
    unsigned short* qkv = base + (size_t)upc * UNIT_ROWS * CH;

    const int smem2 = 4 * 6912 * 2;   // 55,296 B -> 2 blocks/CU
    hipFuncSetAttribute(reinterpret_cast<const void*>(k_attn),
                        hipFuncAttributeMaxDynamicSharedMemorySize, smem2);

    dim3 blk(256);
    k_cvt_w<<<dim3((QKV_N * CH + 255) / 256), blk, 0, stream>>>(qkv_w, proj_w, wq_bt, wp_bt);

    for (int u0 = 0; u0 < 64; u0 += upc) {
        int units = (64 - u0) < upc ? (64 - u0) : upc;
        int m_base = u0 * UNIT_ROWS;
        int Mc = units * UNIT_ROWS;
        int mtiles = (Mc + 127) / 128;
        k_cvt<<<dim3(2048), blk, 0, stream>>>(x + (size_t)m_base * CH, xb, Mc * 48);
        k_gemm<0><<<dim3(mtiles * 9), blk, 0, stream>>>(
                xb, CH, wq_bt, CH, qkv_b, qkv, nullptr, QKV_N, Mc, 9, mtiles);
        k_attn<<<dim3(units * 192), blk, smem2, stream>>>(qkv, mask, btab, u0);
        k_gemm<1><<<dim3(mtiles * 3), blk, 0, stream>>>(
                qkv, QKV_N, wp_bt, CH, proj_b, nullptr, out + (size_t)m_base * CH,
                CH, Mc, 3, mtiles);
    }
}